// Round 3
// baseline (292.401 us; speedup 1.0000x reference)
//
#include <hip/hip_runtime.h>

typedef unsigned short ushort_t;
typedef unsigned int uint_t;
typedef __attribute__((ext_vector_type(8))) short bf16x8;
typedef __attribute__((ext_vector_type(4))) float f32x4;

#define C_DIM 64
#define P_DIM 1296
#define N_DIM 2000
#define B_DIM 256
#define K_DIM (C_DIM * P_DIM)               // 82944
#define XB_ELEMS (B_DIM * K_DIM)            // 21233664
#define XB_ELEMS_PAD (XB_ELEMS + 256)       // 21233920
#define XB_BYTES ((size_t)XB_ELEMS_PAD * 2) // 42467840
#define SLICES 32
#define OUT_ELEMS (B_DIM * N_DIM)           // 512000
#define NSTEP 82                            // 2 channels x 41 BK=32 steps

static __device__ __forceinline__ ushort_t f2bf(float f) {
  unsigned u = __builtin_bit_cast(unsigned, f);
  u += 0x7fffu + ((u >> 16) & 1u);
  return (ushort_t)(u >> 16);
}

// ---------------- x (fp32) -> Xb (bf16) with zeroed pad tail ----------------
__global__ void klindt_cvt_kernel(const float4* __restrict__ x,
                                  unsigned long long* __restrict__ xb) {
  int idx = blockIdx.x * 256 + threadIdx.x;
  if (idx >= XB_ELEMS_PAD / 4) return;
  unsigned long long r = 0ull;
  if (idx < XB_ELEMS / 4) {
    float4 v = x[idx];
    r = (unsigned long long)f2bf(v.x) | ((unsigned long long)f2bf(v.y) << 16) |
        ((unsigned long long)f2bf(v.z) << 32) |
        ((unsigned long long)f2bf(v.w) << 48);
  }
  xb[idx] = r;
}

// ---------------- main GEMM: partials[slice][b][n] ----------------
// H1 fix: 256-thread blocks (4 waves, 2Mx2N), BM=128, BN=128, BK=32.
// Grid 32x32 = 1024 blocks = 4 independent barrier domains per CU, so one
// block's compute/barrier phase is covered by the other 3 blocks' loads.
// mw is still read exactly once from HBM (m-pair blocks share via L2/L3).
__global__ void __launch_bounds__(256, 4) klindt_gemm_kernel(
    const char* __restrict__ xbb, const char* __restrict__ mwb,
    const float* __restrict__ rw, float* __restrict__ partials) {
  __shared__ ushort_t sA[2][4096];  // [128 m][32 k] bf16, 64B rows, XOR-swz
  __shared__ ushort_t sB[2][4096];  // [128 n][32 k] bf16, 64B rows, XOR-swz

  const int tid = threadIdx.x;
  const int lane = tid & 63;
  const int wid = tid >> 6;   // 0..3
  const int wm = wid >> 1;    // 0..1
  const int wn = wid & 1;     // 0..1
  const int nt = blockIdx.x & 15;
  const int mt = blockIdx.x >> 4;
  const int n0 = nt * 128;
  const int m0 = mt * 128;
  const int slice = blockIdx.y;
  const int c0 = slice * 2;

  f32x4 acc[4][4];
#pragma unroll
  for (int i = 0; i < 4; ++i)
#pragma unroll
    for (int j = 0; j < 4; ++j) {
      acc[i][j][0] = 0.f; acc[i][j][1] = 0.f;
      acc[i][j][2] = 0.f; acc[i][j][3] = 0.f;
    }

  // ---- A staging: linear LDS dest, inverse-swizzled global src (rule #21) --
  uint_t a_gbase[2]; int a_doff[2];
#pragma unroll
  for (int it = 0; it < 2; ++it) {
    int chunk = it * 256 + tid;
    int row = chunk >> 2, t4 = chunk & 3;
    int ss = t4 ^ ((row >> 1) & 3);
    a_gbase[it] = (uint_t)((m0 + row) * K_DIM + ss * 8) * 2u;  // bytes in xb
    a_doff[it] = chunk * 8;                                    // elems in sA
  }
  // ---- B staging: 4 its of (1 n, 4 p) per thread ----
  uint_t b_goff[4]; int b_eoff[4], b_kq[4];
  float rvl[4], rvh[4];
#pragma unroll
  for (int it = 0; it < 4; ++it) {
    int idx = it * 256 + tid;
    int nl = idx & 15, kq = (idx >> 4) & 7, nh = idx >> 7;
    int n = nh * 16 + nl;
    int ng = n0 + n;
    int ngc = ng < (N_DIM - 1) ? ng : (N_DIM - 1);  // clamp addr; zero via rw
    b_kq[it] = kq;
    b_goff[it] = (uint_t)kq * 2048000u + (uint_t)ngc * 4u;  // bytes in mw
    int slotp = (kq >> 1) ^ ((nl >> 1) & 3);
    b_eoff[it] = n * 32 + slotp * 8 + (kq & 1) * 4;  // elems in sB
    bool okn = ng < N_DIM;
    rvl[it] = okn ? rw[c0 * N_DIM + ng] : 0.f;
    rvh[it] = okn ? rw[(c0 + 1) * N_DIM + ng] : 0.f;
  }

  // ---- fragment read offsets (swizzle-consistent) ----
  const int r15 = lane & 15, g4 = lane >> 4;
  const int swz = g4 ^ ((r15 >> 1) & 3);
  const int aoffbase = (wm * 64 + r15) * 32 + swz * 8;
  const int boffbase = (wn * 64 + r15) * 32 + swz * 8;

  float mv[4][4];

  auto issueA = [&](int buf, int t) {
    int half = (t >= 41) ? 1 : 0;
    int sp = t - 41 * half;
    uint_t kb = ((uint_t)(c0 + half) * (uint_t)P_DIM + (uint_t)sp * 32u) * 2u;
#pragma unroll
    for (int it = 0; it < 2; ++it) {
      const char* g = xbb + (a_gbase[it] + kb);
      __builtin_amdgcn_global_load_lds(
          (const __attribute__((address_space(1))) unsigned int*)g,
          (__attribute__((address_space(3))) unsigned int*)(&sA[buf][a_doff[it]]),
          16, 0, 0);
    }
  };
  auto issueB = [&](int t) {
    int half = (t >= 41) ? 1 : 0;
    int sp = t - 41 * half;
    uint_t ub = (uint_t)sp * 16384000u + (uint_t)(c0 + half) * 8000u;
    if (sp < 40) {  // uniform branch: all p in range
#pragma unroll
      for (int it = 0; it < 4; ++it) {
        const char* bp = mwb + (ub + b_goff[it]);
#pragma unroll
        for (int j = 0; j < 4; ++j)
          mv[it][j] = *(const float*)(bp + (uint_t)j * 512000u);
      }
    } else {  // sp == 40: only p0+0..15 valid (P=1296=40*32+16)
#pragma unroll
      for (int it = 0; it < 4; ++it) {
        const char* bp = mwb + (ub + b_goff[it]);
#pragma unroll
        for (int j = 0; j < 4; ++j) {
          bool ok = (b_kq[it] * 4 + j) < 16;
          mv[it][j] = ok ? *(const float*)(bp + (uint_t)j * 512000u) : 0.f;
        }
      }
    }
  };
  auto writeB = [&](int buf, int t) {
    bool hi = (t >= 41);
#pragma unroll
    for (int it = 0; it < 4; ++it) {
      float r = hi ? rvh[it] : rvl[it];
      unsigned long long pk = 0ull;
#pragma unroll
      for (int j = 0; j < 4; ++j)
        pk |= (unsigned long long)f2bf(mv[it][j] * r) << (16 * j);
      *(unsigned long long*)(&sB[buf][b_eoff[it]]) = pk;
    }
  };
  auto computeStep = [&](int buf) {
    bf16x8 bfr[4];
#pragma unroll
    for (int fn = 0; fn < 4; ++fn)
      bfr[fn] = *(const bf16x8*)(&sB[buf][boffbase + fn * 512]);
#pragma unroll
    for (int fm = 0; fm < 4; ++fm) {
      bf16x8 afr = *(const bf16x8*)(&sA[buf][aoffbase + fm * 512]);
#pragma unroll
      for (int fn = 0; fn < 4; ++fn)
        acc[fm][fn] = __builtin_amdgcn_mfma_f32_16x16x32_bf16(
            afr, bfr[fn], acc[fm][fn], 0, 0, 0);
    }
  };

  // ---- prologue: stage step 0 into buf 0 ----
  issueB(0);
  issueA(0, 0);
  writeB(0, 0);
  __syncthreads();

  for (int s = 0; s < NSTEP - 1; ++s) {
    int buf = s & 1;
    issueB(s + 1);           // 16 dword loads -> regs (issue early)
    issueA(buf ^ 1, s + 1);  // async global -> LDS
    computeStep(buf);        // ds_read + MFMA hides load latency
    writeB(buf ^ 1, s + 1);  // cvt + ds_write (write late)
    __syncthreads();
  }
  computeStep((NSTEP - 1) & 1);

  // ---- epilogue: fp32 partials for this K-slice ----
  float* pb = partials + (size_t)slice * OUT_ELEMS;
#pragma unroll
  for (int fm = 0; fm < 4; ++fm) {
#pragma unroll
    for (int fn = 0; fn < 4; ++fn) {
      int nn = n0 + wn * 64 + fn * 16 + r15;
      if (nn < N_DIM) {
#pragma unroll
        for (int rr = 0; rr < 4; ++rr) {
          int m = m0 + wm * 64 + fm * 16 + g4 * 4 + rr;
          pb[m * N_DIM + nn] = acc[fm][fn][rr];
        }
      }
    }
  }
}

// ---------------- deterministic split-K reduction ----------------
__global__ void klindt_reduce_kernel(const float* __restrict__ part,
                                     float* __restrict__ out) {
  int i = blockIdx.x * 256 + threadIdx.x;
  if (i < OUT_ELEMS) {
    float s = 0.f;
#pragma unroll
    for (int k = 0; k < SLICES; ++k) s += part[(size_t)k * OUT_ELEMS + i];
    out[i] = s;
  }
}

extern "C" void kernel_launch(void* const* d_in, const int* in_sizes, int n_in,
                              void* d_out, int out_size, void* d_ws,
                              size_t ws_size, hipStream_t stream) {
  (void)in_sizes; (void)n_in; (void)out_size; (void)ws_size;
  const float* x = (const float*)d_in[0];
  const char* mwb = (const char*)d_in[1];
  const float* rw = (const float*)d_in[2];
  float* out = (float*)d_out;

  char* xbb = (char*)d_ws;
  float* partials = (float*)((char*)d_ws + XB_BYTES);

  {
    int nvec = XB_ELEMS_PAD / 4;
    int grid = (nvec + 255) / 256;
    klindt_cvt_kernel<<<grid, 256, 0, stream>>>((const float4*)x,
                                                (unsigned long long*)xbb);
  }
  {
    dim3 grid(32, SLICES);  // (16 n-tiles x 2 m-tiles, 32 K-slices)
    klindt_gemm_kernel<<<grid, 256, 0, stream>>>(xbb, mwb, rw, partials);
  }
  {
    int grid = (OUT_ELEMS + 255) / 256;
    klindt_reduce_kernel<<<grid, 256, 0, stream>>>(partials, out);
  }
}

// Round 5
// 240.138 us; speedup vs baseline: 1.2176x; 1.2176x over previous
//
#include <hip/hip_runtime.h>

typedef unsigned short ushort_t;
typedef unsigned int uint_t;
typedef __attribute__((ext_vector_type(8))) short bf16x8;
typedef __attribute__((ext_vector_type(4))) float f32x4;

#define C_DIM 64
#define P_DIM 1296
#define N_DIM 2000
#define B_DIM 256
#define K_DIM (C_DIM * P_DIM)               // 82944
#define XB_ELEMS (B_DIM * K_DIM)            // 21233664
#define XB_ELEMS_PAD (XB_ELEMS + 256)       // 21233920
#define XB_BYTES ((size_t)XB_ELEMS_PAD * 2) // 42467840
#define SLICES 32
#define OUT_ELEMS (B_DIM * N_DIM)           // 512000
#define NSTEP 82                            // 2 channels x 41 BK=32 steps

static __device__ __forceinline__ ushort_t f2bf(float f) {
  unsigned u = __builtin_bit_cast(unsigned, f);
  u += 0x7fffu + ((u >> 16) & 1u);
  return (ushort_t)(u >> 16);
}

// ---------------- x (fp32) -> Xb (bf16) with zeroed pad tail ----------------
__global__ void klindt_cvt_kernel(const float4* __restrict__ x,
                                  unsigned long long* __restrict__ xb) {
  int idx = blockIdx.x * 256 + threadIdx.x;
  if (idx >= XB_ELEMS_PAD / 4) return;
  unsigned long long r = 0ull;
  if (idx < XB_ELEMS / 4) {
    float4 v = x[idx];
    r = (unsigned long long)f2bf(v.x) | ((unsigned long long)f2bf(v.y) << 16) |
        ((unsigned long long)f2bf(v.z) << 32) |
        ((unsigned long long)f2bf(v.w) << 48);
  }
  xb[idx] = r;
}

// ---------------- main GEMM: partials[slice][b][n] ----------------
// BM=256 (full M, mw read exactly once), BN=128, BK=32. 512 threads = 8 waves
// (4Mx2N), wave tile 64x64 = acc[4][4] of 16x16x32 bf16 MFMAs.
// T4 fix (H2): explicit vmcnt(16) leaves ALL 16 B-prefetch loads in flight
// across the barrier (waits only the 4 A global_load_lds). The mw HBM stream
// never drains -> no chip-wide burst lockstep.
__global__ void __launch_bounds__(512, 4) klindt_gemm_kernel(
    const char* __restrict__ xbb, const char* __restrict__ mwb,
    const float* __restrict__ rw, float* __restrict__ partials) {
  __shared__ ushort_t sA[2][8192];  // [256 m][32 k] bf16, 64B rows, XOR-swz
  __shared__ ushort_t sB[2][4096];  // [128 n][32 k] bf16, 64B rows, XOR-swz

  const int tid = threadIdx.x;
  const int lane = tid & 63;
  const int wid = tid >> 6;
  const int wm = wid >> 1;
  const int wn = wid & 1;
  const int n0 = blockIdx.x * 128;
  const int slice = blockIdx.y;
  const int c0 = slice * 2;

  f32x4 acc[4][4];
#pragma unroll
  for (int i = 0; i < 4; ++i)
#pragma unroll
    for (int j = 0; j < 4; ++j) {
      acc[i][j][0] = 0.f; acc[i][j][1] = 0.f;
      acc[i][j][2] = 0.f; acc[i][j][3] = 0.f;
    }

  // ---- A staging: linear LDS dest, inverse-swizzled global src (rule #21) --
  uint_t a_gbase[2]; int a_doff[2];
#pragma unroll
  for (int it = 0; it < 2; ++it) {
    int chunk = it * 512 + tid;
    int row = chunk >> 2, t4 = chunk & 3;
    int ss = t4 ^ ((row >> 1) & 3);
    a_gbase[it] = (uint_t)(row * K_DIM + ss * 8) * 2u;  // byte off into xb
    a_doff[it] = chunk * 8;                             // elem off into sA
  }
  // ---- B staging constants (addresses clamped; OOB-n zeroed via rv=0) ----
  uint_t b_goff[2]; int b_eoff[2], b_kj[2];
  float rvl[2], rvh[2];
#pragma unroll
  for (int it = 0; it < 2; ++it) {
    int idx = it * 512 + tid;
    int nl = idx & 15, kq = (idx >> 4) & 7, nh = idx >> 7;
    int n = nh * 16 + nl;
    int ng = n0 + n;
    int ngc = ng < (N_DIM - 1) ? ng : (N_DIM - 1);  // clamp addr
    bool okn = ng < N_DIM;
    b_kj[it] = kq * 4;
    b_goff[it] = (uint_t)kq * 2048000u + (uint_t)ngc * 4u;  // byte off into mw
    int slotp = (kq >> 1) ^ ((nl >> 1) & 3);
    b_eoff[it] = n * 32 + slotp * 8 + (kq & 1) * 4;         // elem off into sB
    rvl[it] = okn ? rw[c0 * N_DIM + ng] : 0.f;
    rvh[it] = okn ? rw[(c0 + 1) * N_DIM + ng] : 0.f;
  }

  // ---- fragment read offsets (swizzle-consistent) ----
  const int r15 = lane & 15, g4 = lane >> 4;
  const int swz = g4 ^ ((r15 >> 1) & 3);
  const int aoffbase = (wm * 64 + r15) * 32 + swz * 8;
  const int boffbase = (wn * 64 + r15) * 32 + swz * 8;

  float mvE[2][4], mvO[2][4];  // B register double-buffer (static parity)

  auto issueA = [&](int buf, int t) {
    int half = (t >= 41) ? 1 : 0;
    int sp = t - 41 * half;
    uint_t kb = ((uint_t)(c0 + half) * (uint_t)P_DIM + (uint_t)sp * 32u) * 2u;
#pragma unroll
    for (int it = 0; it < 2; ++it) {
      const char* g = xbb + (a_gbase[it] + kb);
      __builtin_amdgcn_global_load_lds(
          (const __attribute__((address_space(1))) unsigned int*)g,
          (__attribute__((address_space(3))) unsigned int*)(&sA[buf][a_doff[it]]),
          16, 0, 0);
    }
  };
  auto computeStep = [&](int buf) {
    bf16x8 bfr[4];
#pragma unroll
    for (int fn = 0; fn < 4; ++fn)
      bfr[fn] = *(const bf16x8*)(&sB[buf][boffbase + fn * 512]);
    __builtin_amdgcn_s_setprio(1);
#pragma unroll
    for (int fm = 0; fm < 4; ++fm) {
      bf16x8 afr = *(const bf16x8*)(&sA[buf][aoffbase + fm * 512]);
#pragma unroll
      for (int fn = 0; fn < 4; ++fn)
        acc[fm][fn] = __builtin_amdgcn_mfma_f32_16x16x32_bf16(
            afr, bfr[fn], acc[fm][fn], 0, 0, 0);
    }
    __builtin_amdgcn_s_setprio(0);
  };

#define ISSUE_B(MV, T)                                                        \
  do {                                                                        \
    int half_ = ((T) >= 41) ? 1 : 0;                                          \
    int sp_ = (T)-41 * half_;                                                 \
    uint_t ub_ = (uint_t)sp_ * 16384000u + (uint_t)(c0 + half_) * 8000u;      \
    if (sp_ < 40) { /* uniform: all p in range, no per-elem select */         \
      _Pragma("unroll") for (int it_ = 0; it_ < 2; ++it_) {                   \
        const char* bp_ = mwb + (ub_ + b_goff[it_]);                          \
        _Pragma("unroll") for (int j_ = 0; j_ < 4; ++j_)                      \
          MV[it_][j_] = *(const float*)(bp_ + (uint_t)j_ * 512000u);          \
      }                                                                       \
    } else { /* sp==40: only first 16 k valid */                              \
      _Pragma("unroll") for (int it_ = 0; it_ < 2; ++it_) {                   \
        const char* bp_ = mwb + (ub_ + b_goff[it_]);                          \
        _Pragma("unroll") for (int j_ = 0; j_ < 4; ++j_) {                    \
          bool ok_ = (b_kj[it_] + j_) < 16;                                   \
          MV[it_][j_] = ok_ ? *(const float*)(bp_ + (uint_t)j_ * 512000u)     \
                            : 0.f;                                            \
        }                                                                     \
      }                                                                       \
    }                                                                         \
  } while (0)

#define WRITE_B(BUF, MV, T)                                                   \
  do {                                                                        \
    bool hi_ = ((T) >= 41);                                                   \
    _Pragma("unroll") for (int it_ = 0; it_ < 2; ++it_) {                     \
      float r_ = hi_ ? rvh[it_] : rvl[it_];                                   \
      unsigned long long pk_ = 0ull;                                          \
      _Pragma("unroll") for (int j_ = 0; j_ < 4; ++j_)                        \
        pk_ |= (unsigned long long)f2bf(MV[it_][j_] * r_) << (16 * j_);       \
      *(unsigned long long*)(&sB[BUF][b_eoff[it_]]) = pk_;                    \
    }                                                                         \
  } while (0)

  // ---- prologue ----
  ISSUE_B(mvE, 0);
  issueA(0, 0);
  WRITE_B(0, mvE, 0);  // implicit wait drains B(0); A(0) stays in flight
  ISSUE_B(mvO, 1);
  asm volatile("s_waitcnt vmcnt(16) lgkmcnt(0)" ::: "memory");
  __builtin_amdgcn_sched_barrier(0);
  __builtin_amdgcn_s_barrier();
  __builtin_amdgcn_sched_barrier(0);

#define BODY(S, MV_ISSUE, MV_WRITE)                                           \
  {                                                                           \
    issueA(((S) + 1) & 1, (S) + 1);                                           \
    ISSUE_B(MV_ISSUE, (S) + 2);                                               \
    computeStep((S)&1);                                                       \
    WRITE_B(((S) + 1) & 1, MV_WRITE, (S) + 1);                                \
    asm volatile("s_waitcnt vmcnt(16) lgkmcnt(0)" ::: "memory");              \
    __builtin_amdgcn_sched_barrier(0);                                        \
    __builtin_amdgcn_s_barrier();                                             \
    __builtin_amdgcn_sched_barrier(0);                                        \
  }

  // ---- main loop: steps 0..79 ----
  for (int s = 0; s < 80; s += 2) {
    BODY(s, mvE, mvO);
    BODY(s + 1, mvO, mvE);
  }
  // ---- peel s=80 (no B prefetch; full drain so A(81) is guaranteed) ----
  issueA(1, 81);
  computeStep(0);
  WRITE_B(1, mvO, 81);
  asm volatile("s_waitcnt vmcnt(0) lgkmcnt(0)" ::: "memory");
  __builtin_amdgcn_sched_barrier(0);
  __builtin_amdgcn_s_barrier();
  __builtin_amdgcn_sched_barrier(0);
  // ---- s=81 ----
  computeStep(1);

  // ---- epilogue: fp32 partials for this K-slice ----
  float* pb = partials + (size_t)slice * OUT_ELEMS;
#pragma unroll
  for (int fm = 0; fm < 4; ++fm) {
#pragma unroll
    for (int fn = 0; fn < 4; ++fn) {
      int nn = n0 + wn * 64 + fn * 16 + r15;
      if (nn < N_DIM) {
#pragma unroll
        for (int rr = 0; rr < 4; ++rr) {
          int m = wm * 64 + fm * 16 + g4 * 4 + rr;
          pb[m * N_DIM + nn] = acc[fm][fn][rr];
        }
      }
    }
  }
#undef BODY
#undef ISSUE_B
#undef WRITE_B
}

// ---------------- deterministic split-K reduction ----------------
__global__ void klindt_reduce_kernel(const float* __restrict__ part,
                                     float* __restrict__ out) {
  int i = blockIdx.x * 256 + threadIdx.x;
  if (i < OUT_ELEMS) {
    float s = 0.f;
#pragma unroll
    for (int k = 0; k < SLICES; ++k) s += part[(size_t)k * OUT_ELEMS + i];
    out[i] = s;
  }
}

extern "C" void kernel_launch(void* const* d_in, const int* in_sizes, int n_in,
                              void* d_out, int out_size, void* d_ws,
                              size_t ws_size, hipStream_t stream) {
  (void)in_sizes; (void)n_in; (void)out_size; (void)ws_size;
  const float* x = (const float*)d_in[0];
  const char* mwb = (const char*)d_in[1];
  const float* rw = (const float*)d_in[2];
  float* out = (float*)d_out;

  char* xbb = (char*)d_ws;
  float* partials = (float*)((char*)d_ws + XB_BYTES);

  {
    int nvec = XB_ELEMS_PAD / 4;
    int grid = (nvec + 255) / 256;
    klindt_cvt_kernel<<<grid, 256, 0, stream>>>((const float4*)x,
                                                (unsigned long long*)xbb);
  }
  {
    dim3 grid(16, SLICES);
    klindt_gemm_kernel<<<grid, 512, 0, stream>>>(xbb, mwb, rw, partials);
  }
  {
    int grid = (OUT_ELEMS + 255) / 256;
    klindt_reduce_kernel<<<grid, 256, 0, stream>>>(partials, out);
  }
}

// Round 6
// 225.169 us; speedup vs baseline: 1.2986x; 1.0665x over previous
//
#include <hip/hip_runtime.h>

typedef unsigned short ushort_t;
typedef unsigned int uint_t;
typedef __attribute__((ext_vector_type(8))) short bf16x8;
typedef __attribute__((ext_vector_type(4))) float f32x4;

#define C_DIM 64
#define P_DIM 1296
#define N_DIM 2000
#define B_DIM 256
#define K_DIM (C_DIM * P_DIM)               // 82944
#define XB_ELEMS (B_DIM * K_DIM)            // 21233664
#define XB_ELEMS_PAD (XB_ELEMS + 256)       // 21233920
#define XB_BYTES ((size_t)XB_ELEMS_PAD * 2) // 42467840
#define SLICES 32
#define OUT_ELEMS (B_DIM * N_DIM)           // 512000
#define NSTEP 82                            // 2 channels x 41 BK=32 steps

static __device__ __forceinline__ ushort_t f2bf(float f) {
  unsigned u = __builtin_bit_cast(unsigned, f);
  u += 0x7fffu + ((u >> 16) & 1u);
  return (ushort_t)(u >> 16);
}

// ---------------- x (fp32) -> Xb (bf16) with zeroed pad tail ----------------
__global__ void klindt_cvt_kernel(const float4* __restrict__ x,
                                  unsigned long long* __restrict__ xb) {
  int idx = blockIdx.x * 256 + threadIdx.x;
  if (idx >= XB_ELEMS_PAD / 4) return;
  unsigned long long r = 0ull;
  if (idx < XB_ELEMS / 4) {
    float4 v = x[idx];
    r = (unsigned long long)f2bf(v.x) | ((unsigned long long)f2bf(v.y) << 16) |
        ((unsigned long long)f2bf(v.z) << 32) |
        ((unsigned long long)f2bf(v.w) << 48);
  }
  xb[idx] = r;
}

// ---------------- main GEMM: partials[slice][b][n] ----------------
// BM=256 (full M, mw read exactly once), BN=128, BK=32. 512 threads = 8 waves
// (4Mx2N), wave tile 64x64 = acc[4][4] of 16x16x32 bf16 MFMAs.
// H9 fix: XCD-pinned placement — all 16 n-tile blocks of one K-slice land on
// the same XCD (wgid%8 round-robin heuristic), so the 16x re-read of that
// slice's A-tiles is served by the XCD's 4 MB L2 (128 KB live set), not
// HBM/L3. Cuts far-memory traffic from ~1.33 GB to ~0.75 GB.
// Race fix: barrier wait is vmcnt(8) — drains exactly the 4 A global_load_lds
// (B's 8 prefetch loads stay in flight across the barrier, T4 style).
__global__ void __launch_bounds__(512, 4) klindt_gemm_kernel(
    const char* __restrict__ xbb, const char* __restrict__ mwb,
    const float* __restrict__ rw, float* __restrict__ partials) {
  __shared__ ushort_t sA[2][8192];  // [256 m][32 k] bf16, 64B rows, XOR-swz
  __shared__ ushort_t sB[2][4096];  // [128 n][32 k] bf16, 64B rows, XOR-swz

  const int tid = threadIdx.x;
  const int lane = tid & 63;
  const int wid = tid >> 6;
  const int wm = wid >> 1;
  const int wn = wid & 1;
  // XCD-pinned decode: xcd = bid&7 (empirical round-robin), slice in
  // {xcd, xcd+8, xcd+16, xcd+24}, 16 n-tiles of a slice share one XCD's L2.
  const int bid = blockIdx.x;
  const int slice = (bid & 7) + 8 * ((bid >> 3) & 3);  // 0..31
  const int n0 = (bid >> 5) * 128;                     // 16 n-tiles
  const int c0 = slice * 2;

  f32x4 acc[4][4];
#pragma unroll
  for (int i = 0; i < 4; ++i)
#pragma unroll
    for (int j = 0; j < 4; ++j) {
      acc[i][j][0] = 0.f; acc[i][j][1] = 0.f;
      acc[i][j][2] = 0.f; acc[i][j][3] = 0.f;
    }

  // ---- A staging: linear LDS dest, inverse-swizzled global src (rule #21) --
  uint_t a_gbase[2]; int a_doff[2];
#pragma unroll
  for (int it = 0; it < 2; ++it) {
    int chunk = it * 512 + tid;
    int row = chunk >> 2, t4 = chunk & 3;
    int ss = t4 ^ ((row >> 1) & 3);
    a_gbase[it] = (uint_t)(row * K_DIM + ss * 8) * 2u;  // byte off into xb
    a_doff[it] = chunk * 8;                             // elem off into sA
  }
  // ---- B staging constants (addresses clamped; OOB-n zeroed via rv=0) ----
  uint_t b_goff[2]; int b_eoff[2], b_kj[2];
  float rvl[2], rvh[2];
#pragma unroll
  for (int it = 0; it < 2; ++it) {
    int idx = it * 512 + tid;
    int nl = idx & 15, kq = (idx >> 4) & 7, nh = idx >> 7;
    int n = nh * 16 + nl;
    int ng = n0 + n;
    int ngc = ng < (N_DIM - 1) ? ng : (N_DIM - 1);  // clamp addr
    bool okn = ng < N_DIM;
    b_kj[it] = kq * 4;
    b_goff[it] = (uint_t)kq * 2048000u + (uint_t)ngc * 4u;  // byte off into mw
    int slotp = (kq >> 1) ^ ((nl >> 1) & 3);
    b_eoff[it] = n * 32 + slotp * 8 + (kq & 1) * 4;         // elem off into sB
    rvl[it] = okn ? rw[c0 * N_DIM + ng] : 0.f;
    rvh[it] = okn ? rw[(c0 + 1) * N_DIM + ng] : 0.f;
  }

  // ---- fragment read offsets (swizzle-consistent) ----
  const int r15 = lane & 15, g4 = lane >> 4;
  const int swz = g4 ^ ((r15 >> 1) & 3);
  const int aoffbase = (wm * 64 + r15) * 32 + swz * 8;
  const int boffbase = (wn * 64 + r15) * 32 + swz * 8;

  float mvE[2][4], mvO[2][4];  // B register double-buffer (static parity)

  auto issueA = [&](int buf, int t) {
    int half = (t >= 41) ? 1 : 0;
    int sp = t - 41 * half;
    uint_t kb = ((uint_t)(c0 + half) * (uint_t)P_DIM + (uint_t)sp * 32u) * 2u;
#pragma unroll
    for (int it = 0; it < 2; ++it) {
      const char* g = xbb + (a_gbase[it] + kb);
      __builtin_amdgcn_global_load_lds(
          (const __attribute__((address_space(1))) unsigned int*)g,
          (__attribute__((address_space(3))) unsigned int*)(&sA[buf][a_doff[it]]),
          16, 0, 0);
    }
  };
  auto computeStep = [&](int buf) {
    bf16x8 bfr[4];
#pragma unroll
    for (int fn = 0; fn < 4; ++fn)
      bfr[fn] = *(const bf16x8*)(&sB[buf][boffbase + fn * 512]);
    __builtin_amdgcn_s_setprio(1);
#pragma unroll
    for (int fm = 0; fm < 4; ++fm) {
      bf16x8 afr = *(const bf16x8*)(&sA[buf][aoffbase + fm * 512]);
#pragma unroll
      for (int fn = 0; fn < 4; ++fn)
        acc[fm][fn] = __builtin_amdgcn_mfma_f32_16x16x32_bf16(
            afr, bfr[fn], acc[fm][fn], 0, 0, 0);
    }
    __builtin_amdgcn_s_setprio(0);
  };

#define ISSUE_B(MV, T)                                                        \
  do {                                                                        \
    int half_ = ((T) >= 41) ? 1 : 0;                                          \
    int sp_ = (T)-41 * half_;                                                 \
    uint_t ub_ = (uint_t)sp_ * 16384000u + (uint_t)(c0 + half_) * 8000u;      \
    if (sp_ < 40) { /* uniform: all p in range, no per-elem select */         \
      _Pragma("unroll") for (int it_ = 0; it_ < 2; ++it_) {                   \
        const char* bp_ = mwb + (ub_ + b_goff[it_]);                          \
        _Pragma("unroll") for (int j_ = 0; j_ < 4; ++j_)                      \
          MV[it_][j_] = *(const float*)(bp_ + (uint_t)j_ * 512000u);          \
      }                                                                       \
    } else { /* sp==40: only first 16 k valid */                              \
      _Pragma("unroll") for (int it_ = 0; it_ < 2; ++it_) {                   \
        const char* bp_ = mwb + (ub_ + b_goff[it_]);                          \
        _Pragma("unroll") for (int j_ = 0; j_ < 4; ++j_) {                    \
          bool ok_ = (b_kj[it_] + j_) < 16;                                   \
          MV[it_][j_] = ok_ ? *(const float*)(bp_ + (uint_t)j_ * 512000u)     \
                            : 0.f;                                            \
        }                                                                     \
      }                                                                       \
    }                                                                         \
  } while (0)

#define WRITE_B(BUF, MV, T)                                                   \
  do {                                                                        \
    bool hi_ = ((T) >= 41);                                                   \
    _Pragma("unroll") for (int it_ = 0; it_ < 2; ++it_) {                     \
      float r_ = hi_ ? rvh[it_] : rvl[it_];                                   \
      unsigned long long pk_ = 0ull;                                          \
      _Pragma("unroll") for (int j_ = 0; j_ < 4; ++j_)                        \
        pk_ |= (unsigned long long)f2bf(MV[it_][j_] * r_) << (16 * j_);       \
      *(unsigned long long*)(&sB[BUF][b_eoff[it_]]) = pk_;                    \
    }                                                                         \
  } while (0)

  // ---- prologue ----
  ISSUE_B(mvE, 0);
  issueA(0, 0);
  WRITE_B(0, mvE, 0);  // implicit wait drains B(0); A(0) stays in flight
  ISSUE_B(mvO, 1);
  asm volatile("s_waitcnt vmcnt(8) lgkmcnt(0)" ::: "memory");
  __builtin_amdgcn_sched_barrier(0);
  __builtin_amdgcn_s_barrier();
  __builtin_amdgcn_sched_barrier(0);

#define BODY(S, MV_ISSUE, MV_WRITE)                                           \
  {                                                                           \
    issueA(((S) + 1) & 1, (S) + 1);                                           \
    ISSUE_B(MV_ISSUE, (S) + 2);                                               \
    computeStep((S)&1);                                                       \
    WRITE_B(((S) + 1) & 1, MV_WRITE, (S) + 1);                                \
    asm volatile("s_waitcnt vmcnt(8) lgkmcnt(0)" ::: "memory");               \
    __builtin_amdgcn_sched_barrier(0);                                        \
    __builtin_amdgcn_s_barrier();                                             \
    __builtin_amdgcn_sched_barrier(0);                                        \
  }

  // ---- main loop: steps 0..79 ----
  for (int s = 0; s < 80; s += 2) {
    BODY(s, mvE, mvO);
    BODY(s + 1, mvO, mvE);
  }
  // ---- peel s=80 (no B prefetch; full drain so A(81) is guaranteed) ----
  issueA(1, 81);
  computeStep(0);
  WRITE_B(1, mvO, 81);
  asm volatile("s_waitcnt vmcnt(0) lgkmcnt(0)" ::: "memory");
  __builtin_amdgcn_sched_barrier(0);
  __builtin_amdgcn_s_barrier();
  __builtin_amdgcn_sched_barrier(0);
  // ---- s=81 ----
  computeStep(1);

  // ---- epilogue: fp32 partials for this K-slice ----
  float* pb = partials + (size_t)slice * OUT_ELEMS;
#pragma unroll
  for (int fm = 0; fm < 4; ++fm) {
#pragma unroll
    for (int fn = 0; fn < 4; ++fn) {
      int nn = n0 + wn * 64 + fn * 16 + r15;
      if (nn < N_DIM) {
#pragma unroll
        for (int rr = 0; rr < 4; ++rr) {
          int m = wm * 64 + fm * 16 + g4 * 4 + rr;
          pb[m * N_DIM + nn] = acc[fm][fn][rr];
        }
      }
    }
  }
#undef BODY
#undef ISSUE_B
#undef WRITE_B
}

// ---------------- deterministic split-K reduction ----------------
__global__ void klindt_reduce_kernel(const float* __restrict__ part,
                                     float* __restrict__ out) {
  int i = blockIdx.x * 256 + threadIdx.x;
  if (i < OUT_ELEMS) {
    float s = 0.f;
#pragma unroll
    for (int k = 0; k < SLICES; ++k) s += part[(size_t)k * OUT_ELEMS + i];
    out[i] = s;
  }
}

extern "C" void kernel_launch(void* const* d_in, const int* in_sizes, int n_in,
                              void* d_out, int out_size, void* d_ws,
                              size_t ws_size, hipStream_t stream) {
  (void)in_sizes; (void)n_in; (void)out_size; (void)ws_size;
  const float* x = (const float*)d_in[0];
  const char* mwb = (const char*)d_in[1];
  const float* rw = (const float*)d_in[2];
  float* out = (float*)d_out;

  char* xbb = (char*)d_ws;
  float* partials = (float*)((char*)d_ws + XB_BYTES);

  {
    int nvec = XB_ELEMS_PAD / 4;
    int grid = (nvec + 255) / 256;
    klindt_cvt_kernel<<<grid, 256, 0, stream>>>((const float4*)x,
                                                (unsigned long long*)xbb);
  }
  {
    klindt_gemm_kernel<<<512, 512, 0, stream>>>(xbb, mwb, rw, partials);
  }
  {
    int grid = (OUT_ELEMS + 255) / 256;
    klindt_reduce_kernel<<<grid, 256, 0, stream>>>(partials, out);
  }
}